// Round 1
// baseline (8348.415 us; speedup 1.0000x reference)
//
#include <hip/hip_runtime.h>

typedef __attribute__((ext_vector_type(8))) short bf16x8;
typedef __attribute__((ext_vector_type(4))) float f32x4;

#define L2E 1.4426950408889634f

__device__ __forceinline__ short f2bf(float x){
  unsigned u = __builtin_bit_cast(unsigned, x);
  u += 0x7fffu + ((u >> 16) & 1u);
  return (short)(u >> 16);
}
__device__ __forceinline__ float sigm(float x){
  float e = __builtin_amdgcn_exp2f(-x * L2E);
  return __builtin_amdgcn_rcpf(1.0f + e);
}
__device__ __forceinline__ float tanh_(float x){
  float e = __builtin_amdgcn_exp2f(x * (2.0f * L2E));
  return 1.0f - 2.0f * __builtin_amdgcn_rcpf(1.0f + e);
}

// Main recurrence kernel: 256 WGs x 512 threads. WG handles 16 batch rows.
// Wave w owns hidden units [16w,16w+16) for both cells; Whh in registers (bf16).
__global__ __launch_bounds__(512, 2)
void rios_main(const float* __restrict__ values, const float* __restrict__ masks,
               const float* __restrict__ deltas,
               const float* __restrict__ Wih0, const float* __restrict__ Whh0,
               const float* __restrict__ bih0, const float* __restrict__ bhh0,
               const float* __restrict__ Wih1, const float* __restrict__ Whh1,
               const float* __restrict__ bih1, const float* __restrict__ bhh1,
               const float* __restrict__ td_W, const float* __restrict__ td_b,
               const float* __restrict__ hr_W, const float* __restrict__ hr_b,
               float* __restrict__ out, float* __restrict__ lossws)
{
  __shared__ short hb[2][16][136];   // h A-operand ping-pong: [buf][batch m][unit k], +8 pad
  __shared__ float xh_part[8][16];   // per-wave partial of h0 . hr_W, per batch m
  __shared__ float xc_s[16];         // broadcast x_c (written by wave 0)
  __shared__ float sA[2][5][16][16]; // scalar chunks: [buf][v0,v1,v2,mask,delta2][tt][m]

  const int tid = threadIdx.x;
  const int w  = tid >> 6;
  const int l  = tid & 63;
  const int q  = l >> 4;
  const int c  = l & 15;
  const int q4 = q << 2;
  const int u  = (w << 4) + c;
  const long long bb = (long long)blockIdx.x * 16;

  // ---- persistent weight fragments (B-operand layout: col=lane&15, k=(lane>>4)*8+j)
  bf16x8 wf[2][4][4];   // [cell: 0=lstm1, 1=lstm0][gate][ktile]
  {
    const float* WhhA[2] = { Whh1, Whh0 };
    #pragma unroll
    for (int cell = 0; cell < 2; ++cell)
      #pragma unroll
      for (int gi = 0; gi < 4; ++gi)
        #pragma unroll
        for (int kt = 0; kt < 4; ++kt){
          const float* rp = WhhA[cell] + (((gi << 7) + u) << 7) + (kt << 5) + (q << 3);
          bf16x8 f;
          #pragma unroll
          for (int j = 0; j < 8; ++j) f[j] = f2bf(rp[j]);
          wf[cell][gi][kt] = f;
        }
  }
  float wi[2][4][2], bs[2][4];
  {
    const float* WihA[2] = { Wih1, Wih0 };
    const float* bihA[2] = { bih1, bih0 };
    const float* bhhA[2] = { bhh1, bhh0 };
    #pragma unroll
    for (int cell = 0; cell < 2; ++cell)
      #pragma unroll
      for (int gi = 0; gi < 4; ++gi){
        int rg = (gi << 7) + u;
        wi[cell][gi][0] = WihA[cell][rg * 2];
        wi[cell][gi][1] = WihA[cell][rg * 2 + 1];
        bs[cell][gi]    = bihA[cell][rg] + bhhA[cell][rg];
      }
  }
  const float tdw = td_W[u], tdbv = td_b[u], hrw = hr_W[u], hrb = hr_b[0];

  // ---- zero initial state in LDS
  {
    short* hz = &hb[0][0][0];
    for (int i = tid; i < 16 * 136; i += 512) hz[i] = 0;
    if (tid < 128) ((float*)xh_part)[tid] = 0.f;
  }

  // ---- chunk loader thread roles (16 steps of scalars per chunk)
  const int isV = (tid < 192);
  const int isD = (tid >= 192 && tid < 384);
  const int isM = (tid >= 384 && tid < 448);
  int lb = 0, lp = 0;
  if (isV){ lb = tid / 12;        lp = tid % 12; }
  else if (isD){ lb = (tid-192)/12; lp = (tid-192)%12; }
  else if (isM){ lb = (tid-384)/4;  lp = (tid-384)%4; }
  const float* ldbase = nullptr;
  if (isV)      ldbase = values + ((bb + lb) * 2048LL) * 3 + lp * 4;
  else if (isD) ldbase = deltas + ((bb + lb) * 2048LL) * 3 + lp * 4;
  else if (isM) ldbase = masks  +  (bb + lb) * 2048LL      + lp * 4;

  auto write_stage = [&](int buf, f32x4 r){
    if (isV){
      #pragma unroll
      for (int j = 0; j < 4; ++j){ int idx = lp * 4 + j; sA[buf][idx % 3][idx / 3][lb] = r[j]; }
    } else if (isD){
      #pragma unroll
      for (int j = 0; j < 4; ++j){ int idx = lp * 4 + j; if (idx % 3 == 2) sA[buf][4][idx / 3][lb] = r[j]; }
    } else if (isM){
      #pragma unroll
      for (int j = 0; j < 4; ++j){ sA[buf][3][lp * 4 + j][lb] = r[j]; }
    }
  };

  // prologue: chunk 0
  if (tid < 448){
    f32x4 st = *(const f32x4*)(ldbase);
    write_stage(0, st);
  }
  __syncthreads();

  f32x4 c1 = {0.f, 0.f, 0.f, 0.f};

  for (int cc = 0; cc < 128; ++cc){
    const int cb = cc & 1;
    f32x4 nst;
    if (cc + 1 < 128 && tid < 448){
      long long t0 = (long long)(cc + 1) * 16;
      nst = *(const f32x4*)(ldbase + (isM ? t0 : t0 * 3));
    }
    #pragma unroll 2
    for (int tt = 0; tt < 16; ++tt){
      const int t = (cc << 4) + tt;
      const int p = tt & 1;

      // ================= phase A : cell1 (+ wave0: x_h / x_c / loss) ===========
      f32x4 v0v = *(const f32x4*)&sA[cb][0][tt][q4];
      f32x4 v1v = *(const f32x4*)&sA[cb][1][tt][q4];
      f32x4 dv  = *(const f32x4*)&sA[cb][4][tt][q4];
      f32x4 acc[4];
      #pragma unroll
      for (int gi = 0; gi < 4; ++gi){
        #pragma unroll
        for (int r = 0; r < 4; ++r)
          acc[gi][r] = fmaf(v0v[r], wi[0][gi][0], fmaf(v1v[r], wi[0][gi][1], bs[0][gi]));
      }
      #pragma unroll
      for (int kt = 0; kt < 4; ++kt){
        bf16x8 af = *(const bf16x8*)&hb[p][c][(kt << 5) + (q << 3)];
        #pragma unroll
        for (int gi = 0; gi < 4; ++gi)
          acc[gi] = __builtin_amdgcn_mfma_f32_16x16x32_bf16(af, wf[0][gi][kt], acc[gi], 0, 0, 0);
      }

      if (w == 0){
        f32x4 xh = { hrb, hrb, hrb, hrb };
        #pragma unroll
        for (int w2 = 0; w2 < 8; ++w2)
          xh += *(const f32x4*)&xh_part[w2][q4];
        f32x4 xy = *(const f32x4*)&sA[cb][2][tt][q4];
        f32x4 mm = *(const f32x4*)&sA[cb][3][tt][q4];
        f32x4 xc = mm * xy + (1.f - mm) * xh;
        f32x4 df = xy - xh;
        f32x4 wv = df * df * mm;
        if (c == 0) *((f32x4*)&xc_s[q4]) = xc;
        float xcsel = (c == 0) ? xc[0] : ((c == 1) ? xc[1] : ((c == 2) ? xc[2] : xc[3]));
        if (c < 4) out[1 + (bb + q4 + c) * 2048LL + t] = xcsel;
        float swse = wv[0] + wv[1] + wv[2] + wv[3];
        float smm  = mm[0] + mm[1] + mm[2] + mm[3];
        swse += __shfl_xor(swse, 16); swse += __shfl_xor(swse, 32);
        smm  += __shfl_xor(smm, 16);  smm  += __shfl_xor(smm, 32);
        if (l == 0){ atomicAdd(&lossws[2 * t], swse); atomicAdd(&lossws[2 * t + 1], smm); }
      }

      #pragma unroll
      for (int r = 0; r < 4; ++r){
        float si = sigm(acc[0][r]);
        float sf = sigm(acc[1][r]);
        float tg = tanh_(acc[2][r]);
        float so = sigm(acc[3][r]);
        float c2 = sf * c1[r] + si * tg;
        float a1 = fmaxf(fmaf(dv[r], tdw, tdbv), 0.f);
        float gam = __builtin_amdgcn_exp2f(-a1 * L2E);
        float h1n = so * tanh_(c2) * gam;
        c1[r] = c2;
        hb[p ^ 1][q4 + r][u] = f2bf(h1n);
      }
      __syncthreads();   // barrier 1: h1n + xc_s published

      // ================= phase B : cell0 =======================================
      f32x4 xcv = *(const f32x4*)&xc_s[q4];
      f32x4 mmv = *(const f32x4*)&sA[cb][3][tt][q4];
      #pragma unroll
      for (int gi = 0; gi < 4; ++gi){
        #pragma unroll
        for (int r = 0; r < 4; ++r)
          acc[gi][r] = fmaf(xcv[r], wi[1][gi][0], fmaf(mmv[r], wi[1][gi][1], bs[1][gi]));
      }
      #pragma unroll
      for (int kt = 0; kt < 4; ++kt){
        bf16x8 af = *(const bf16x8*)&hb[p ^ 1][c][(kt << 5) + (q << 3)];
        #pragma unroll
        for (int gi = 0; gi < 4; ++gi)
          acc[gi] = __builtin_amdgcn_mfma_f32_16x16x32_bf16(af, wf[1][gi][kt], acc[gi], 0, 0, 0);
      }
      f32x4 pv;
      #pragma unroll
      for (int r = 0; r < 4; ++r){
        float si = sigm(acc[0][r]);
        float sf = sigm(acc[1][r]);
        float tg = tanh_(acc[2][r]);
        float so = sigm(acc[3][r]);
        float c0n = sf * c1[r] + si * tg;   // c input = c1n (updated), not overwritten
        float h0n = so * tanh_(c0n);
        pv[r] = h0n * hrw;
      }
      #pragma unroll
      for (int mk = 1; mk < 16; mk <<= 1){
        #pragma unroll
        for (int r = 0; r < 4; ++r) pv[r] += __shfl_xor(pv[r], mk);
      }
      if (c == 0) *((f32x4*)&xh_part[w][q4]) = pv;
      __syncthreads();   // barrier 2: xh_part published for next step
    }
    if (cc + 1 < 128 && tid < 448) write_stage(cb ^ 1, nst);
    __syncthreads();     // publish next scalar chunk
  }
}

__global__ void loss_reduce(const float* __restrict__ lossws, float* __restrict__ out){
  __shared__ float red[1024];
  int t = threadIdx.x;
  float v = lossws[2 * t] / (lossws[2 * t + 1] + 1e-5f)
          + lossws[2 * (t + 1024)] / (lossws[2 * (t + 1024) + 1] + 1e-5f);
  red[t] = v;
  __syncthreads();
  for (int s = 512; s > 0; s >>= 1){
    if (t < s) red[t] += red[t + s];
    __syncthreads();
  }
  if (t == 0) out[0] = red[0];
}

__global__ void copy_outs(const float* __restrict__ values, const float* __restrict__ masks,
                          const float* __restrict__ evalm, float* __restrict__ out){
  const long long M = 8388608LL; // 4096*2048
  long long i = (long long)blockIdx.x * 256 + threadIdx.x;
  if (i < M){
    out[1 + M     + i] = evalm[i];
    out[1 + 2 * M + i] = values[3 * i + 2];
    out[1 + 3 * M + i] = masks[i];
  }
}

extern "C" void kernel_launch(void* const* d_in, const int* in_sizes, int n_in,
                              void* d_out, int out_size, void* d_ws, size_t ws_size,
                              hipStream_t stream){
  const float* values = (const float*)d_in[0];
  const float* masks  = (const float*)d_in[1];
  const float* deltas = (const float*)d_in[2];
  const float* evalm  = (const float*)d_in[3];
  const float* Wih0   = (const float*)d_in[4];
  const float* Whh0   = (const float*)d_in[5];
  const float* bih0   = (const float*)d_in[6];
  const float* bhh0   = (const float*)d_in[7];
  const float* Wih1   = (const float*)d_in[8];
  const float* Whh1   = (const float*)d_in[9];
  const float* bih1   = (const float*)d_in[10];
  const float* bhh1   = (const float*)d_in[11];
  const float* td_W   = (const float*)d_in[12];
  const float* td_b   = (const float*)d_in[13];
  const float* hr_W   = (const float*)d_in[14];
  const float* hr_b   = (const float*)d_in[15];
  float* out    = (float*)d_out;
  float* lossws = (float*)d_ws;

  hipMemsetAsync(lossws, 0, 2048 * 2 * sizeof(float), stream);
  hipLaunchKernelGGL(copy_outs, dim3(32768), dim3(256), 0, stream, values, masks, evalm, out);
  hipLaunchKernelGGL(rios_main, dim3(256), dim3(512), 0, stream,
                     values, masks, deltas, Wih0, Whh0, bih0, bhh0,
                     Wih1, Whh1, bih1, bhh1, td_W, td_b, hr_W, hr_b, out, lossws);
  hipLaunchKernelGGL(loss_reduce, dim3(1), dim3(1024), 0, stream, lossws, out);
}